// Round 17
// baseline (538.072 us; speedup 1.0000x reference)
//
#include <hip/hip_runtime.h>

// LSTMPINN fused kernel, round 31: R30 + register diet to tip 3 waves/SIMD.
// R30 post-mortem: VALUBusy 30.5->27.8 with NO time change -> VALU/trans off critical
// path; kernel is latency-bound at 2 wave ctx/SIMD (116 arch + 64 AGPR = 180/wave,
// floor(512/180)=2). Last lever: total <=168 -> 3 waves/SIMD (occ 23.5->35%). The
// 12-reg gap is exactly the persistent wih0v/b0v/b1v arrays (used only at acc-init).
// Fix: re-load per use via VOLATILE loads (defeats LICM; arrays are 2KB L1-resident;
// loads issued pre-barrier / under pw1 so latency hides) + amdgpu_waves_per_eu(3,3).
// Values recomputed identically -> bit-identical (absmax 1.525879e-05).
// Gates: VGPR_Count <=104 and OccupancyPercent ~35, WRITE_SIZE ~1MB.

typedef __attribute__((ext_vector_type(8))) short bf16x8;
typedef __attribute__((ext_vector_type(4))) float f32x4;

#define TM 64          // samples per block
#define APAD 8
#define AS (256 + APAD) // A-plane row stride in ushorts

// ws layout (ushort units):
// LSTM B: hi-only row-major (PRE-SCALED by log2e / 2log2e per gate).
// Dense: interleaved hi/lo per 8-elem chunk (PRE-SCALED by 2log2e). Out: unscaled.
#define OFF_HH0 0        // 512x128 hi-only
#define OFF_L1  65536    // 512x256 hi-only (cat Wih1|Whh1)
#define OFF_D0  196608   // 256x256 interleaved (cols permuted: k<128 -> mean)
#define OFF_D1  327680
#define OFF_D2  458752
#define OFF_OUT 589824   // 16x256 interleaved (rows 4..15 zero)

#define K1F 1.4426950408889634f   // log2(e)
#define K2F 2.8853900817779268f   // 2*log2(e)

__device__ __forceinline__ unsigned short f2bf(float x) {
  union { float f; unsigned u; } v; v.f = x;
  unsigned r = v.u + 0x7fffu + ((v.u >> 16) & 1u);   // RNE
  return (unsigned short)(r >> 16);
}
__device__ __forceinline__ float bf2f(unsigned short b) {
  union { unsigned u; float f; } v; v.u = ((unsigned)b) << 16; return v.f;
}
__device__ __forceinline__ float asf(unsigned v) {
  union { unsigned u; float f; } w; w.u = v; return w.f;
}
__device__ __forceinline__ float vld(const float* p) {   // volatile: no LICM/CSE
  return *(volatile const float*)p;
}
__device__ __forceinline__ float rcp_(float v) { return __builtin_amdgcn_rcpf(v); }
__device__ __forceinline__ float exp2_(float v) {
  float r; asm("v_exp_f32 %0, %1" : "=v"(r) : "v"(v)); return r;
}
__device__ __forceinline__ float exp2n_(float v) {
  float r; asm("v_exp_f32 %0, -%1" : "=v"(r) : "v"(v)); return r;
}
__device__ __forceinline__ unsigned cvtpk(float lo, float hi) {
  unsigned r; asm("v_cvt_pk_bf16_f32 %0, %1, %2" : "=v"(r) : "v"(lo), "v"(hi)); return r;
}
// dense tanh (input pre-scaled by 2log2e)
__device__ __forceinline__ float tanh_s(float v) { return 1.f - 2.f * rcp_(exp2_(v) + 1.f); }

// ---------------- prep (x4 vectorized): LSTM hi-only; dense interleaved hi/lo --------
__global__ void prep_k(const float* __restrict__ Whh0, const float* __restrict__ Wih1,
                       const float* __restrict__ Whh1, const float* __restrict__ Wd0,
                       const float* __restrict__ Wd1, const float* __restrict__ Wd2,
                       const float* __restrict__ Wout, unsigned short* __restrict__ ws) {
  int id = (blockIdx.x * 256 + threadIdx.x) * 4;
  if (id >= 397312) return;
  if (id < 65536) {                       // W_hh_l0 [512][128] hi-only, gate-scaled
    int row = id >> 7;                    // 4-pack stays in one row (id%4==0)
    float sc = ((row >> 7) == 2) ? K2F : K1F;
    const float4 w = *(const float4*)(Whh0 + id);
    ushort4 h;
    h.x = f2bf(w.x * sc); h.y = f2bf(w.y * sc);
    h.z = f2bf(w.z * sc); h.w = f2bf(w.w * sc);
    *(ushort4*)(ws + OFF_HH0 + id) = h;
    return;
  }
  if (id < 196608) {                      // B_l1 [512][256] = cat(Wih1,Whh1), gate-scaled
    int i = id - 65536;
    int r = i >> 8, k = i & 255;          // pack same row, same side of k=128
    const float* src = (k < 128) ? (Wih1 + (r << 7) + k) : (Whh1 + (r << 7) + k - 128);
    const float4 w = *(const float4*)src;
    float sc = ((r >> 7) == 2) ? K2F : K1F;
    ushort4 h;
    h.x = f2bf(w.x * sc); h.y = f2bf(w.y * sc);
    h.z = f2bf(w.z * sc); h.w = f2bf(w.w * sc);
    *(ushort4*)(ws + OFF_L1 + i) = h;
    return;
  }
  float4 w; int base, r, k;
  if (id < 262144) {                      // Bd0 [256][256], permute: our k<128 = mean
    int i = id - 196608; r = i >> 8; k = i & 255; base = OFF_D0;
    int kk = (k < 128) ? k + 128 : k - 128;
    w = *(const float4*)(Wd0 + (r << 8) + kk);
  } else if (id < 327680) {               // Bd1
    int i = id - 262144; r = i >> 8; k = i & 255; base = OFF_D1;
    w = *(const float4*)(Wd1 + i);
  } else if (id < 393216) {               // Bd2
    int i = id - 327680; r = i >> 8; k = i & 255; base = OFF_D2;
    w = *(const float4*)(Wd2 + i);
  } else {                                // Bout [16][256], rows >=4 zero (UNscaled)
    int i = id - 393216; r = i >> 8; k = i & 255; base = OFF_OUT;
    if (r < 4) w = *(const float4*)(Wout + (r << 8) + k);
    else { w.x = 0.f; w.y = 0.f; w.z = 0.f; w.w = 0.f; }
  }
  if (base != OFF_OUT) {                  // dense layers feed tanh_s
    w.x *= K2F; w.y *= K2F; w.z *= K2F; w.w *= K2F;
  }
  ushort4 h, l;
  h.x = f2bf(w.x); l.x = f2bf(w.x - bf2f(h.x));
  h.y = f2bf(w.y); l.y = f2bf(w.y - bf2f(h.y));
  h.z = f2bf(w.z); l.z = f2bf(w.z - bf2f(h.z));
  h.w = f2bf(w.w); l.w = f2bf(w.w - bf2f(h.w));
  // k%8 in {0,4} -> 4 consecutive slots within one 8-chunk
  int off = base + r * 512 + ((k >> 3) << 4) + (k & 7);
  *(ushort4*)(ws + off) = h;
  *(ushort4*)(ws + off + 8) = l;
}

// ------- 1-term GEMM (LSTM): B hi-only row-major, A hi-only, acc += Ah*Bh -------
template <int NT, int KITERS, int UNROLL>
__device__ __forceinline__ void gemm1t(const unsigned short* __restrict__ B,
                                       const int ldB, const int* cols,
                                       const unsigned short (*Ah)[AS],
                                       int l16, int quad, f32x4 (&acc)[4][4]) {
  const unsigned short* bp[NT];
#pragma unroll
  for (int n = 0; n < NT; ++n)
    bp[n] = B + (size_t)(cols[n] + l16) * ldB + quad * 8;
  const unsigned short* aph = &Ah[l16][quad * 8];
#pragma unroll UNROLL
  for (int ki = 0; ki < KITERS; ++ki) {
    bf16x8 bh[NT];
#pragma unroll
    for (int n = 0; n < NT; ++n) {
      bh[n] = *(const bf16x8*)(bp[n]);
      bp[n] += 32;
    }
    bf16x8 afh[4];
#pragma unroll
    for (int m = 0; m < 4; ++m)
      afh[m] = *(const bf16x8*)(aph + m * 16 * AS);
#pragma unroll
    for (int n = 0; n < NT; ++n)
#pragma unroll
      for (int m = 0; m < 4; ++m)
        acc[m][n] = __builtin_amdgcn_mfma_f32_16x16x32_bf16(afh[m], bh[n], acc[m][n], 0, 0, 0);
    aph += 32;
  }
}

// ------- 3-term split GEMM (dense): interleaved hi/lo B -------
template <int NT, int KITERS, int UNROLL>
__device__ __forceinline__ void gemm3t(const unsigned short* __restrict__ B,
                                       const int ldB2, const int* cols,
                                       const unsigned short (*Ah)[AS],
                                       const unsigned short (*Al)[AS],
                                       int l16, int quad, f32x4 (&acc)[4][4]) {
  const unsigned short* bp[NT];
#pragma unroll
  for (int n = 0; n < NT; ++n)
    bp[n] = B + (size_t)(cols[n] + l16) * ldB2 + quad * 16;
  const unsigned short* aph = &Ah[l16][quad * 8];
  const unsigned short* apl = &Al[l16][quad * 8];
#pragma unroll UNROLL
  for (int ki = 0; ki < KITERS; ++ki) {
    bf16x8 bh[NT], bl[NT];
#pragma unroll
    for (int n = 0; n < NT; ++n) {
      bh[n] = *(const bf16x8*)(bp[n]);
      bl[n] = *(const bf16x8*)(bp[n] + 8);
      bp[n] += 64;
    }
    bf16x8 afh[4], afl[4];
#pragma unroll
    for (int m = 0; m < 4; ++m) {
      afh[m] = *(const bf16x8*)(aph + m * 16 * AS);
      afl[m] = *(const bf16x8*)(apl + m * 16 * AS);
    }
#pragma unroll
    for (int n = 0; n < NT; ++n)
#pragma unroll
      for (int m = 0; m < 4; ++m)
        acc[m][n] = __builtin_amdgcn_mfma_f32_16x16x32_bf16(afh[m], bh[n], acc[m][n], 0, 0, 0);
#pragma unroll
    for (int n = 0; n < NT; ++n)
#pragma unroll
      for (int m = 0; m < 4; ++m)
        acc[m][n] = __builtin_amdgcn_mfma_f32_16x16x32_bf16(afl[m], bh[n], acc[m][n], 0, 0, 0);
#pragma unroll
    for (int n = 0; n < NT; ++n)
#pragma unroll
      for (int m = 0; m < 4; ++m)
        acc[m][n] = __builtin_amdgcn_mfma_f32_16x16x32_bf16(afh[m], bl[n], acc[m][n], 0, 0, 0);
    aph += 32;
    apl += 32;
  }
}

// ---------------- main fused kernel: 1 block = 64 samples, 8 waves, full network -------
__global__ __launch_bounds__(512) __attribute__((amdgpu_waves_per_eu(3, 3))) void fused_k(
    const float* __restrict__ x, const float* __restrict__ y,
    const float* __restrict__ Wih0, const float* __restrict__ b0,
    const float* __restrict__ b1, const float* __restrict__ bd0,
    const float* __restrict__ bd1, const float* __restrict__ bd2,
    const float* __restrict__ bout, const unsigned short* __restrict__ wsu,
    float* __restrict__ out) {
  // Two hi planes only. LSTM: ping-pong [h0_t | h1_{t-1}]. After t=5:
  // plane0 = [mean-hi | last-hi], plane1 = [mean-lo | last-lo]; dense runs in-place.
  __shared__ unsigned short Ahi[2][TM][AS];
  __shared__ float feats[6][TM];

  const int tid = threadIdx.x;
  const int wv = tid >> 6;     // wave 0..7
  const int lane = tid & 63;
  const int quad = lane >> 4;  // 0..3
  const int l16 = lane & 15;
  const int u = 16 * wv + l16; // this lane's LSTM unit (0..127)
  const int sb = blockIdx.x * TM;

  if (tid < TM) {
    float xn = 2.f * x[sb + tid] - 1.f;
    float yn = 2.f * y[sb + tid] - 1.f;
    feats[0][tid] = xn; feats[1][tid] = yn; feats[2][tid] = xn + yn;
    feats[3][tid] = xn - yn; feats[4][tid] = xn * yn; feats[5][tid] = xn * xn + yn * yn;
  }

  // per-lane state: [m][r] -> sample s=16m+4quad+r, unit u. c-state in K2-scaled domain.
  float c0[4][4], c1[4][4], meanh[4][4];
#pragma unroll
  for (int m = 0; m < 4; ++m)
#pragma unroll
    for (int r = 0; r < 4; ++r) { c0[m][r] = 0.f; c1[m][r] = 0.f; meanh[m][r] = 0.f; }

  int colsL[4];  // gate-type n -> col block
#pragma unroll
  for (int n = 0; n < 4; ++n) colsL[n] = 128 * n + 16 * wv;

  __syncthreads();  // feats visible

  f32x4 acc[4][4];

  // ---- prologue: pw0(t=0): c=0 path, shared-rcp form; h0_0 -> plane 0 (hi) ----
  {
    float w0[4], bb[4];
#pragma unroll
    for (int n = 0; n < 4; ++n) {
      const float sc = (n == 2) ? K2F : K1F;
      w0[n] = vld(Wih0 + 128 * n + u) * sc;
      bb[n] = vld(b0 + 128 * n + u) * sc;
    }
#pragma unroll
    for (int m = 0; m < 4; ++m)
#pragma unroll
      for (int rp = 0; rp < 2; ++rp) {
        float hx[2];
#pragma unroll
        for (int q2 = 0; q2 < 2; ++q2) {
          const int r = 2 * rp + q2;
          const float xf = feats[0][16 * m + 4 * quad + r];
          float zi = xf * w0[0] + bb[0];
          float zg = xf * w0[2] + bb[2];
          float zo = xf * w0[3] + bb[3];
          float Ai = 1.f + exp2n_(zi);
          float Eg = exp2_(zg);
          float Ag = Eg + 1.f;
          float Ngk = __builtin_fmaf(Eg, K2F, -K2F);   // K2*(Eg-1)
          float ccs = Ngk * rcp_(Ai * Ag);             // = K2 * i * g  (c was 0)
          c0[m][r] = ccs;
          float Eo = exp2n_(zo);
          float Ec = exp2_(ccs);
          hx[q2] = (Ec - 1.f) * rcp_((1.f + Eo) * (Ec + 1.f));  // o * tanh(c)
        }
        unsigned pk = cvtpk(hx[0], hx[1]);
        const int s0 = 16 * m + 4 * quad + 2 * rp;
        Ahi[0][s0][u] = (unsigned short)pk;
        Ahi[0][s0 + 1][u] = (unsigned short)(pk >> 16);
      }
  }

  // ---- main loop t=0..4 (t=5 peeled). Plane p = t&1 holds [h0_t | h1_{t-1}]. ----
#pragma unroll 1
  for (int t = 0; t < 5; ++t) {
    const int p = t & 1;
    const int pn = p ^ 1;

    // b1 re-load (volatile, ephemeral): issued pre-barrier so latency hides
    float b1t[4];
#pragma unroll
    for (int n = 0; n < 4; ++n)
      b1t[n] = vld(b1 + 128 * n + u) * ((n == 2) ? K2F : K1F);

    __syncthreads();  // h0_t (and h1_{t-1}) visible in plane p; WAR for plane pn writes

    // gemm1(t): gates1 = [h0_t ; h1_{t-1}] @ [Wih1;Whh1]^T + b1   (1-term)
#pragma unroll
    for (int m = 0; m < 4; ++m)
#pragma unroll
      for (int n = 0; n < 4; ++n)
#pragma unroll
        for (int r = 0; r < 4; ++r) acc[m][n][r] = b1t[n];
    if (t == 0)
      gemm1t<4, 4, 1>(wsu + OFF_L1, 256, colsL, Ahi[p], l16, quad, acc);
    else
      gemm1t<4, 8, 2>(wsu + OFF_L1, 256, colsL, Ahi[p], l16, quad, acc);

    // gemm0 weights re-load (volatile, ephemeral): latency hides under pw1
    float wt[4], bt[4];
#pragma unroll
    for (int n = 0; n < 4; ++n) {
      const float sc = (n == 2) ? K2F : K1F;
      wt[n] = vld(Wih0 + 128 * n + u) * sc;
      bt[n] = vld(b0 + 128 * n + u) * sc;
    }

    // pw1(t): shared-rcp LSTM cell; h1_t -> plane pn [128:256) (hi), cvt_pk stores
#pragma unroll
    for (int m = 0; m < 4; ++m)
#pragma unroll
      for (int rp = 0; rp < 2; ++rp) {
        float hx[2];
#pragma unroll
        for (int q2 = 0; q2 < 2; ++q2) {
          const int r = 2 * rp + q2;
          float Ai = 1.f + exp2n_(acc[m][0][r]);
          float Af = 1.f + exp2n_(acc[m][1][r]);
          float Eg = exp2_(acc[m][2][r]);
          float Ag = Eg + 1.f;
          float Ngk = __builtin_fmaf(Eg, K2F, -K2F);
          float P = Ai * Ag;
          float Rr = rcp_(Af * P);
          float ccs = __builtin_fmaf(c1[m][r], P, Ngk * Af) * Rr;
          c1[m][r] = ccs;
          float Eo = exp2n_(acc[m][3][r]);
          float Ec = exp2_(ccs);
          float h = (Ec - 1.f) * rcp_((1.f + Eo) * (Ec + 1.f));
          meanh[m][r] = meanh[m][r] + h;
          hx[q2] = h;
        }
        unsigned pk = cvtpk(hx[0], hx[1]);
        const int s0 = 16 * m + 4 * quad + 2 * rp;
        Ahi[pn][s0][128 + u] = (unsigned short)pk;
        Ahi[pn][s0 + 1][128 + u] = (unsigned short)(pk >> 16);
      }

    // gemm0(t+1): gates0 = x_{t+1}*Wih0 + b0 (C-init) + h0_t @ Whh0^T   (1-term)
#pragma unroll
    for (int m = 0; m < 4; ++m)
#pragma unroll
      for (int r = 0; r < 4; ++r) {
        const float xf = feats[t + 1][16 * m + 4 * quad + r];
#pragma unroll
        for (int n = 0; n < 4; ++n) acc[m][n][r] = xf * wt[n] + bt[n];
      }
    gemm1t<4, 4, 1>(wsu + OFF_HH0, 128, colsL, Ahi[p], l16, quad, acc);

    // pw0(t+1): shared-rcp LSTM cell; h0_{t+1} -> plane pn [0:128) (hi only)
#pragma unroll
    for (int m = 0; m < 4; ++m)
#pragma unroll
      for (int rp = 0; rp < 2; ++rp) {
        float hx[2];
#pragma unroll
        for (int q2 = 0; q2 < 2; ++q2) {
          const int r = 2 * rp + q2;
          float Ai = 1.f + exp2n_(acc[m][0][r]);
          float Af = 1.f + exp2n_(acc[m][1][r]);
          float Eg = exp2_(acc[m][2][r]);
          float Ag = Eg + 1.f;
          float Ngk = __builtin_fmaf(Eg, K2F, -K2F);
          float P = Ai * Ag;
          float Rr = rcp_(Af * P);
          float ccs = __builtin_fmaf(c0[m][r], P, Ngk * Af) * Rr;
          c0[m][r] = ccs;
          float Eo = exp2n_(acc[m][3][r]);
          float Ec = exp2_(ccs);
          hx[q2] = (Ec - 1.f) * rcp_((1.f + Eo) * (Ec + 1.f));
        }
        unsigned pk = cvtpk(hx[0], hx[1]);
        const int s0 = 16 * m + 4 * quad + 2 * rp;
        Ahi[pn][s0][u] = (unsigned short)pk;
        Ahi[pn][s0 + 1][u] = (unsigned short)(pk >> 16);
      }
  }

  // ---- peeled t=5: p=1, pn=0. gemm1(5) reads plane1; hi results -> plane0;
  //      lo values stashed in regs, then written to plane1 after a barrier.
  float b1t5[4];
#pragma unroll
  for (int n = 0; n < 4; ++n)
    b1t5[n] = vld(b1 + 128 * n + u) * ((n == 2) ? K2F : K1F);
  __syncthreads();  // [h0_5 | h1_4] visible in plane 1; plane-0 WAR done
#pragma unroll
  for (int m = 0; m < 4; ++m)
#pragma unroll
    for (int n = 0; n < 4; ++n)
#pragma unroll
      for (int r = 0; r < 4; ++r) acc[m][n][r] = b1t5[n];
  gemm1t<4, 8, 2>(wsu + OFF_L1, 256, colsL, Ahi[1], l16, quad, acc);

  unsigned int lopack[16];  // [4m+r] = cvtpk(last-lo, mean-lo)
#pragma unroll
  for (int m = 0; m < 4; ++m)
#pragma unroll
    for (int rp = 0; rp < 2; ++rp) {
      float hx[2], mn[2];
#pragma unroll
      for (int q2 = 0; q2 < 2; ++q2) {
        const int r = 2 * rp + q2;
        float Ai = 1.f + exp2n_(acc[m][0][r]);
        float Af = 1.f + exp2n_(acc[m][1][r]);
        float Eg = exp2_(acc[m][2][r]);
        float Ag = Eg + 1.f;
        float Ngk = __builtin_fmaf(Eg, K2F, -K2F);
        float P = Ai * Ag;
        float Rr = rcp_(Af * P);
        float ccs = __builtin_fmaf(c1[m][r], P, Ngk * Af) * Rr;
        float Eo = exp2n_(acc[m][3][r]);
        float Ec = exp2_(ccs);
        float h = (Ec - 1.f) * rcp_((1.f + Eo) * (Ec + 1.f));
        hx[q2] = h;
        mn[q2] = (meanh[m][r] + h) * (1.f / 6.f);
      }
      const int s0 = 16 * m + 4 * quad + 2 * rp;
      unsigned pkh = cvtpk(hx[0], hx[1]);
      Ahi[0][s0][128 + u] = (unsigned short)pkh;        // last hi (pair)
      Ahi[0][s0 + 1][128 + u] = (unsigned short)(pkh >> 16);
      unsigned pkm = cvtpk(mn[0], mn[1]);
      Ahi[0][s0][u] = (unsigned short)pkm;              // mean hi (pair)
      Ahi[0][s0 + 1][u] = (unsigned short)(pkm >> 16);
      lopack[4 * m + 2 * rp] =
          cvtpk(hx[0] - asf(pkh << 16), mn[0] - asf(pkm << 16));
      lopack[4 * m + 2 * rp + 1] =
          cvtpk(hx[1] - asf(pkh & 0xffff0000u), mn[1] - asf(pkm & 0xffff0000u));
    }

  __syncthreads();  // all gemm1(5) plane-1 reads done -> safe to overwrite plane 1
#pragma unroll
  for (int m = 0; m < 4; ++m)
#pragma unroll
    for (int r = 0; r < 4; ++r) {
      const int s = 16 * m + 4 * quad + r;
      const unsigned int v = lopack[4 * m + r];
      Ahi[1][s][128 + u] = (unsigned short)(v & 0xffffu);  // last lo
      Ahi[1][s][u] = (unsigned short)(v >> 16);            // mean lo
    }

  // ---- dense head: 3 layers (3-term), IN-PLACE on planes 0(hi)/1(lo) ----
  int colsD[2];
  colsD[0] = 32 * wv; colsD[1] = 32 * wv + 16;

#pragma unroll 1
  for (int layer = 0; layer < 3; ++layer) {
    const int base = (layer == 0) ? OFF_D0 : ((layer == 1) ? OFF_D1 : OFF_D2);
    const float* bd = (layer == 0) ? bd0 : ((layer == 1) ? bd1 : bd2);
    float bdv[2];
#pragma unroll
    for (int n = 0; n < 2; ++n) bdv[n] = bd[colsD[n] + l16] * K2F;
#pragma unroll
    for (int m = 0; m < 4; ++m)
#pragma unroll
      for (int n = 0; n < 2; ++n)
#pragma unroll
        for (int r = 0; r < 4; ++r) acc[m][n][r] = bdv[n];
    __syncthreads();  // prev writes (lo-init / prev layer) visible
    gemm3t<2, 8, 2>(wsu + base, 512, colsD, Ahi[0], Ahi[1], l16, quad, acc);
    __syncthreads();  // all reads of planes 0/1 done before in-place overwrite
#pragma unroll
    for (int m = 0; m < 4; ++m)
#pragma unroll
      for (int r = 0; r < 4; ++r) {
        const int s = 16 * m + 4 * quad + r;
        float a0 = tanh_s(acc[m][0][r]);
        float a1 = tanh_s(acc[m][1][r]);
        unsigned pk = cvtpk(a0, a1);                 // column pair (n=0,1)
        const int ci0 = colsD[0] + l16, ci1 = colsD[1] + l16;
        Ahi[0][s][ci0] = (unsigned short)pk;
        Ahi[0][s][ci1] = (unsigned short)(pk >> 16);
        unsigned pkl = cvtpk(a0 - asf(pk << 16), a1 - asf(pk & 0xffff0000u));
        Ahi[1][s][ci0] = (unsigned short)pkl;
        Ahi[1][s][ci1] = (unsigned short)(pkl >> 16);
      }
  }
  __syncthreads();

  // ---- output layer (3-term): waves 0..3 handle m-tile wv; read planes 0/1 ----
  if (wv < 4) {
    f32x4 oacc = {0.f, 0.f, 0.f, 0.f};
    const unsigned short* bp = wsu + OFF_OUT + (size_t)l16 * 512 + quad * 16;
    const unsigned short* aph = &Ahi[0][16 * wv + l16][quad * 8];
    const unsigned short* apl = &Ahi[1][16 * wv + l16][quad * 8];
#pragma unroll 1
    for (int ki = 0; ki < 8; ++ki) {
      bf16x8 ah = *(const bf16x8*)aph;
      bf16x8 al = *(const bf16x8*)apl;
      bf16x8 bh = *(const bf16x8*)bp;
      bf16x8 bl = *(const bf16x8*)(bp + 8);
      oacc = __builtin_amdgcn_mfma_f32_16x16x32_bf16(ah, bh, oacc, 0, 0, 0);
      oacc = __builtin_amdgcn_mfma_f32_16x16x32_bf16(al, bh, oacc, 0, 0, 0);
      oacc = __builtin_amdgcn_mfma_f32_16x16x32_bf16(ah, bl, oacc, 0, 0, 0);
      aph += 32; apl += 32; bp += 64;
    }
    float bo = (l16 < 4) ? bout[l16] : 0.f;
#pragma unroll
    for (int r = 0; r < 4; ++r) {
      if (l16 < 4) {
        int s = sb + 16 * wv + 4 * quad + r;
        out[s * 4 + l16] = oacc[r] + bo;
      }
    }
  }
}

extern "C" void kernel_launch(void* const* d_in, const int* in_sizes, int n_in,
                              void* d_out, int out_size, void* d_ws, size_t ws_size,
                              hipStream_t stream) {
  (void)in_sizes; (void)n_in; (void)out_size; (void)ws_size;
  const float* x    = (const float*)d_in[0];
  const float* y    = (const float*)d_in[1];
  const float* Wih0 = (const float*)d_in[2];
  const float* Whh0 = (const float*)d_in[3];
  const float* b0   = (const float*)d_in[4];
  const float* Wih1 = (const float*)d_in[5];
  const float* Whh1 = (const float*)d_in[6];
  const float* b1   = (const float*)d_in[7];
  const float* Wd0  = (const float*)d_in[8];
  const float* bd0  = (const float*)d_in[9];
  const float* Wd1  = (const float*)d_in[10];
  const float* bd1  = (const float*)d_in[11];
  const float* Wd2  = (const float*)d_in[12];
  const float* bd2  = (const float*)d_in[13];
  const float* Wout = (const float*)d_in[14];
  const float* bout = (const float*)d_in[15];
  unsigned short* ws = (unsigned short*)d_ws;
  float* out = (float*)d_out;

  prep_k<<<dim3(388), dim3(256), 0, stream>>>(Whh0, Wih1, Whh1, Wd0, Wd1, Wd2, Wout, ws);
  fused_k<<<dim3(65536 / TM), dim3(512), 0, stream>>>(x, y, Wih0, b0, b1, bd0, bd1, bd2,
                                                      bout, ws, out);
}

// Round 18
// 484.498 us; speedup vs baseline: 1.1106x; 1.1106x over previous
//
#include <hip/hip_runtime.h>

// LSTMPINN fused kernel, round 32: PURE REVERT to R30 (best verified: 458us fused).
// R31 post-mortem: 3 waves/SIMD is structurally impossible — 512-thr blocks add waves
// in steps of 2/SIMD (2 or 4 only); 4 needs <=128 total regs (impossible with 64-AGPR
// acc + ~64 arch min); 4-wave blocks need NT=8 (spills, R18). R31's volatile-reload
// diet also spilled (WRITE 26MB) and regressed to 512us. Lever ledger: occupancy
// closed (5 ways), scheduling neutral (3x), load-ILP neutral, VALU/trans diet
// delivered 637->458 and is now decoupled from wall time. This is the converged
// structure: latency-bound at the HW 2-ctx/SIMD wall. absmax 1.525879e-05.

typedef __attribute__((ext_vector_type(8))) short bf16x8;
typedef __attribute__((ext_vector_type(4))) float f32x4;

#define TM 64          // samples per block
#define APAD 8
#define AS (256 + APAD) // A-plane row stride in ushorts

// ws layout (ushort units):
// LSTM B: hi-only row-major (PRE-SCALED by log2e / 2log2e per gate).
// Dense: interleaved hi/lo per 8-elem chunk (PRE-SCALED by 2log2e). Out: unscaled.
#define OFF_HH0 0        // 512x128 hi-only
#define OFF_L1  65536    // 512x256 hi-only (cat Wih1|Whh1)
#define OFF_D0  196608   // 256x256 interleaved (cols permuted: k<128 -> mean)
#define OFF_D1  327680
#define OFF_D2  458752
#define OFF_OUT 589824   // 16x256 interleaved (rows 4..15 zero)

#define K1F 1.4426950408889634f   // log2(e)
#define K2F 2.8853900817779268f   // 2*log2(e)

__device__ __forceinline__ unsigned short f2bf(float x) {
  union { float f; unsigned u; } v; v.f = x;
  unsigned r = v.u + 0x7fffu + ((v.u >> 16) & 1u);   // RNE
  return (unsigned short)(r >> 16);
}
__device__ __forceinline__ float bf2f(unsigned short b) {
  union { unsigned u; float f; } v; v.u = ((unsigned)b) << 16; return v.f;
}
__device__ __forceinline__ float asf(unsigned v) {
  union { unsigned u; float f; } w; w.u = v; return w.f;
}
__device__ __forceinline__ float rcp_(float v) { return __builtin_amdgcn_rcpf(v); }
__device__ __forceinline__ float exp2_(float v) {
  float r; asm("v_exp_f32 %0, %1" : "=v"(r) : "v"(v)); return r;
}
__device__ __forceinline__ float exp2n_(float v) {
  float r; asm("v_exp_f32 %0, -%1" : "=v"(r) : "v"(v)); return r;
}
__device__ __forceinline__ unsigned cvtpk(float lo, float hi) {
  unsigned r; asm("v_cvt_pk_bf16_f32 %0, %1, %2" : "=v"(r) : "v"(lo), "v"(hi)); return r;
}
// dense tanh (input pre-scaled by 2log2e)
__device__ __forceinline__ float tanh_s(float v) { return 1.f - 2.f * rcp_(exp2_(v) + 1.f); }

// ---------------- prep (x4 vectorized): LSTM hi-only; dense interleaved hi/lo --------
__global__ void prep_k(const float* __restrict__ Whh0, const float* __restrict__ Wih1,
                       const float* __restrict__ Whh1, const float* __restrict__ Wd0,
                       const float* __restrict__ Wd1, const float* __restrict__ Wd2,
                       const float* __restrict__ Wout, unsigned short* __restrict__ ws) {
  int id = (blockIdx.x * 256 + threadIdx.x) * 4;
  if (id >= 397312) return;
  if (id < 65536) {                       // W_hh_l0 [512][128] hi-only, gate-scaled
    int row = id >> 7;                    // 4-pack stays in one row (id%4==0)
    float sc = ((row >> 7) == 2) ? K2F : K1F;
    const float4 w = *(const float4*)(Whh0 + id);
    ushort4 h;
    h.x = f2bf(w.x * sc); h.y = f2bf(w.y * sc);
    h.z = f2bf(w.z * sc); h.w = f2bf(w.w * sc);
    *(ushort4*)(ws + OFF_HH0 + id) = h;
    return;
  }
  if (id < 196608) {                      // B_l1 [512][256] = cat(Wih1,Whh1), gate-scaled
    int i = id - 65536;
    int r = i >> 8, k = i & 255;          // pack same row, same side of k=128
    const float* src = (k < 128) ? (Wih1 + (r << 7) + k) : (Whh1 + (r << 7) + k - 128);
    const float4 w = *(const float4*)src;
    float sc = ((r >> 7) == 2) ? K2F : K1F;
    ushort4 h;
    h.x = f2bf(w.x * sc); h.y = f2bf(w.y * sc);
    h.z = f2bf(w.z * sc); h.w = f2bf(w.w * sc);
    *(ushort4*)(ws + OFF_L1 + i) = h;
    return;
  }
  float4 w; int base, r, k;
  if (id < 262144) {                      // Bd0 [256][256], permute: our k<128 = mean
    int i = id - 196608; r = i >> 8; k = i & 255; base = OFF_D0;
    int kk = (k < 128) ? k + 128 : k - 128;
    w = *(const float4*)(Wd0 + (r << 8) + kk);
  } else if (id < 327680) {               // Bd1
    int i = id - 262144; r = i >> 8; k = i & 255; base = OFF_D1;
    w = *(const float4*)(Wd1 + i);
  } else if (id < 393216) {               // Bd2
    int i = id - 327680; r = i >> 8; k = i & 255; base = OFF_D2;
    w = *(const float4*)(Wd2 + i);
  } else {                                // Bout [16][256], rows >=4 zero (UNscaled)
    int i = id - 393216; r = i >> 8; k = i & 255; base = OFF_OUT;
    if (r < 4) w = *(const float4*)(Wout + (r << 8) + k);
    else { w.x = 0.f; w.y = 0.f; w.z = 0.f; w.w = 0.f; }
  }
  if (base != OFF_OUT) {                  // dense layers feed tanh_s
    w.x *= K2F; w.y *= K2F; w.z *= K2F; w.w *= K2F;
  }
  ushort4 h, l;
  h.x = f2bf(w.x); l.x = f2bf(w.x - bf2f(h.x));
  h.y = f2bf(w.y); l.y = f2bf(w.y - bf2f(h.y));
  h.z = f2bf(w.z); l.z = f2bf(w.z - bf2f(h.z));
  h.w = f2bf(w.w); l.w = f2bf(w.w - bf2f(h.w));
  // k%8 in {0,4} -> 4 consecutive slots within one 8-chunk
  int off = base + r * 512 + ((k >> 3) << 4) + (k & 7);
  *(ushort4*)(ws + off) = h;
  *(ushort4*)(ws + off + 8) = l;
}

// ------- 1-term GEMM (LSTM): B hi-only row-major, A hi-only, acc += Ah*Bh -------
template <int NT, int KITERS, int UNROLL>
__device__ __forceinline__ void gemm1t(const unsigned short* __restrict__ B,
                                       const int ldB, const int* cols,
                                       const unsigned short (*Ah)[AS],
                                       int l16, int quad, f32x4 (&acc)[4][4]) {
  const unsigned short* bp[NT];
#pragma unroll
  for (int n = 0; n < NT; ++n)
    bp[n] = B + (size_t)(cols[n] + l16) * ldB + quad * 8;
  const unsigned short* aph = &Ah[l16][quad * 8];
#pragma unroll UNROLL
  for (int ki = 0; ki < KITERS; ++ki) {
    bf16x8 bh[NT];
#pragma unroll
    for (int n = 0; n < NT; ++n) {
      bh[n] = *(const bf16x8*)(bp[n]);
      bp[n] += 32;
    }
    bf16x8 afh[4];
#pragma unroll
    for (int m = 0; m < 4; ++m)
      afh[m] = *(const bf16x8*)(aph + m * 16 * AS);
#pragma unroll
    for (int n = 0; n < NT; ++n)
#pragma unroll
      for (int m = 0; m < 4; ++m)
        acc[m][n] = __builtin_amdgcn_mfma_f32_16x16x32_bf16(afh[m], bh[n], acc[m][n], 0, 0, 0);
    aph += 32;
  }
}

// ------- 3-term split GEMM (dense): interleaved hi/lo B -------
template <int NT, int KITERS, int UNROLL>
__device__ __forceinline__ void gemm3t(const unsigned short* __restrict__ B,
                                       const int ldB2, const int* cols,
                                       const unsigned short (*Ah)[AS],
                                       const unsigned short (*Al)[AS],
                                       int l16, int quad, f32x4 (&acc)[4][4]) {
  const unsigned short* bp[NT];
#pragma unroll
  for (int n = 0; n < NT; ++n)
    bp[n] = B + (size_t)(cols[n] + l16) * ldB2 + quad * 16;
  const unsigned short* aph = &Ah[l16][quad * 8];
  const unsigned short* apl = &Al[l16][quad * 8];
#pragma unroll UNROLL
  for (int ki = 0; ki < KITERS; ++ki) {
    bf16x8 bh[NT], bl[NT];
#pragma unroll
    for (int n = 0; n < NT; ++n) {
      bh[n] = *(const bf16x8*)(bp[n]);
      bl[n] = *(const bf16x8*)(bp[n] + 8);
      bp[n] += 64;
    }
    bf16x8 afh[4], afl[4];
#pragma unroll
    for (int m = 0; m < 4; ++m) {
      afh[m] = *(const bf16x8*)(aph + m * 16 * AS);
      afl[m] = *(const bf16x8*)(apl + m * 16 * AS);
    }
#pragma unroll
    for (int n = 0; n < NT; ++n)
#pragma unroll
      for (int m = 0; m < 4; ++m)
        acc[m][n] = __builtin_amdgcn_mfma_f32_16x16x32_bf16(afh[m], bh[n], acc[m][n], 0, 0, 0);
#pragma unroll
    for (int n = 0; n < NT; ++n)
#pragma unroll
      for (int m = 0; m < 4; ++m)
        acc[m][n] = __builtin_amdgcn_mfma_f32_16x16x32_bf16(afl[m], bh[n], acc[m][n], 0, 0, 0);
#pragma unroll
    for (int n = 0; n < NT; ++n)
#pragma unroll
      for (int m = 0; m < 4; ++m)
        acc[m][n] = __builtin_amdgcn_mfma_f32_16x16x32_bf16(afh[m], bl[n], acc[m][n], 0, 0, 0);
    aph += 32;
    apl += 32;
  }
}

// ---------------- main fused kernel: 1 block = 64 samples, 8 waves, full network -------
__global__ __launch_bounds__(512, 2) void fused_k(
    const float* __restrict__ x, const float* __restrict__ y,
    const float* __restrict__ Wih0, const float* __restrict__ b0,
    const float* __restrict__ b1, const float* __restrict__ bd0,
    const float* __restrict__ bd1, const float* __restrict__ bd2,
    const float* __restrict__ bout, const unsigned short* __restrict__ wsu,
    float* __restrict__ out) {
  // Two hi planes only. LSTM: ping-pong [h0_t | h1_{t-1}]. After t=5:
  // plane0 = [mean-hi | last-hi], plane1 = [mean-lo | last-lo]; dense runs in-place.
  __shared__ unsigned short Ahi[2][TM][AS];
  __shared__ float feats[6][TM];

  const int tid = threadIdx.x;
  const int wv = tid >> 6;     // wave 0..7
  const int lane = tid & 63;
  const int quad = lane >> 4;  // 0..3
  const int l16 = lane & 15;
  const int u = 16 * wv + l16; // this lane's LSTM unit (0..127)
  const int sb = blockIdx.x * TM;

  if (tid < TM) {
    float xn = 2.f * x[sb + tid] - 1.f;
    float yn = 2.f * y[sb + tid] - 1.f;
    feats[0][tid] = xn; feats[1][tid] = yn; feats[2][tid] = xn + yn;
    feats[3][tid] = xn - yn; feats[4][tid] = xn * yn; feats[5][tid] = xn * xn + yn * yn;
  }

  // per-lane weights/biases from global, PRE-SCALED to the exp2 domain
  float wih0v[4], b0v[4], b1v[4];
#pragma unroll
  for (int n = 0; n < 4; ++n) {
    const float sc = (n == 2) ? K2F : K1F;
    wih0v[n] = Wih0[128 * n + u] * sc;
    b0v[n] = b0[128 * n + u] * sc;
    b1v[n] = b1[128 * n + u] * sc;
  }

  // per-lane state: [m][r] -> sample s=16m+4quad+r, unit u. c-state in K2-scaled domain.
  float c0[4][4], c1[4][4], meanh[4][4];
#pragma unroll
  for (int m = 0; m < 4; ++m)
#pragma unroll
    for (int r = 0; r < 4; ++r) { c0[m][r] = 0.f; c1[m][r] = 0.f; meanh[m][r] = 0.f; }

  int colsL[4];  // gate-type n -> col block
#pragma unroll
  for (int n = 0; n < 4; ++n) colsL[n] = 128 * n + 16 * wv;

  __syncthreads();  // feats visible

  f32x4 acc[4][4];

  // ---- prologue: pw0(t=0): c=0 path, shared-rcp form; h0_0 -> plane 0 (hi) ----
#pragma unroll
  for (int m = 0; m < 4; ++m)
#pragma unroll
    for (int rp = 0; rp < 2; ++rp) {
      float hx[2];
#pragma unroll
      for (int q2 = 0; q2 < 2; ++q2) {
        const int r = 2 * rp + q2;
        const float xf = feats[0][16 * m + 4 * quad + r];
        float zi = xf * wih0v[0] + b0v[0];
        float zg = xf * wih0v[2] + b0v[2];
        float zo = xf * wih0v[3] + b0v[3];
        float Ai = 1.f + exp2n_(zi);
        float Eg = exp2_(zg);
        float Ag = Eg + 1.f;
        float Ngk = __builtin_fmaf(Eg, K2F, -K2F);   // K2*(Eg-1)
        float ccs = Ngk * rcp_(Ai * Ag);             // = K2 * i * g  (c was 0)
        c0[m][r] = ccs;
        float Eo = exp2n_(zo);
        float Ec = exp2_(ccs);
        hx[q2] = (Ec - 1.f) * rcp_((1.f + Eo) * (Ec + 1.f));  // o * tanh(c)
      }
      unsigned pk = cvtpk(hx[0], hx[1]);
      const int s0 = 16 * m + 4 * quad + 2 * rp;
      Ahi[0][s0][u] = (unsigned short)pk;
      Ahi[0][s0 + 1][u] = (unsigned short)(pk >> 16);
    }

  // ---- main loop t=0..4 (t=5 peeled). Plane p = t&1 holds [h0_t | h1_{t-1}]. ----
#pragma unroll 1
  for (int t = 0; t < 5; ++t) {
    const int p = t & 1;
    const int pn = p ^ 1;
    __syncthreads();  // h0_t (and h1_{t-1}) visible in plane p; WAR for plane pn writes

    // gemm1(t): gates1 = [h0_t ; h1_{t-1}] @ [Wih1;Whh1]^T + b1   (1-term)
#pragma unroll
    for (int m = 0; m < 4; ++m)
#pragma unroll
      for (int n = 0; n < 4; ++n)
#pragma unroll
        for (int r = 0; r < 4; ++r) acc[m][n][r] = b1v[n];
    if (t == 0)
      gemm1t<4, 4, 1>(wsu + OFF_L1, 256, colsL, Ahi[p], l16, quad, acc);
    else
      gemm1t<4, 8, 2>(wsu + OFF_L1, 256, colsL, Ahi[p], l16, quad, acc);

    // pw1(t): shared-rcp LSTM cell; h1_t -> plane pn [128:256) (hi), cvt_pk stores
#pragma unroll
    for (int m = 0; m < 4; ++m)
#pragma unroll
      for (int rp = 0; rp < 2; ++rp) {
        float hx[2];
#pragma unroll
        for (int q2 = 0; q2 < 2; ++q2) {
          const int r = 2 * rp + q2;
          float Ai = 1.f + exp2n_(acc[m][0][r]);
          float Af = 1.f + exp2n_(acc[m][1][r]);
          float Eg = exp2_(acc[m][2][r]);
          float Ag = Eg + 1.f;
          float Ngk = __builtin_fmaf(Eg, K2F, -K2F);
          float P = Ai * Ag;
          float Rr = rcp_(Af * P);
          float ccs = __builtin_fmaf(c1[m][r], P, Ngk * Af) * Rr;
          c1[m][r] = ccs;
          float Eo = exp2n_(acc[m][3][r]);
          float Ec = exp2_(ccs);
          float h = (Ec - 1.f) * rcp_((1.f + Eo) * (Ec + 1.f));
          meanh[m][r] = meanh[m][r] + h;
          hx[q2] = h;
        }
        unsigned pk = cvtpk(hx[0], hx[1]);
        const int s0 = 16 * m + 4 * quad + 2 * rp;
        Ahi[pn][s0][128 + u] = (unsigned short)pk;
        Ahi[pn][s0 + 1][128 + u] = (unsigned short)(pk >> 16);
      }

    // gemm0(t+1): gates0 = x_{t+1}*Wih0 + b0 (C-init) + h0_t @ Whh0^T   (1-term)
#pragma unroll
    for (int m = 0; m < 4; ++m)
#pragma unroll
      for (int r = 0; r < 4; ++r) {
        const float xf = feats[t + 1][16 * m + 4 * quad + r];
#pragma unroll
        for (int n = 0; n < 4; ++n) acc[m][n][r] = xf * wih0v[n] + b0v[n];
      }
    gemm1t<4, 4, 1>(wsu + OFF_HH0, 128, colsL, Ahi[p], l16, quad, acc);

    // pw0(t+1): shared-rcp LSTM cell; h0_{t+1} -> plane pn [0:128) (hi only)
#pragma unroll
    for (int m = 0; m < 4; ++m)
#pragma unroll
      for (int rp = 0; rp < 2; ++rp) {
        float hx[2];
#pragma unroll
        for (int q2 = 0; q2 < 2; ++q2) {
          const int r = 2 * rp + q2;
          float Ai = 1.f + exp2n_(acc[m][0][r]);
          float Af = 1.f + exp2n_(acc[m][1][r]);
          float Eg = exp2_(acc[m][2][r]);
          float Ag = Eg + 1.f;
          float Ngk = __builtin_fmaf(Eg, K2F, -K2F);
          float P = Ai * Ag;
          float Rr = rcp_(Af * P);
          float ccs = __builtin_fmaf(c0[m][r], P, Ngk * Af) * Rr;
          c0[m][r] = ccs;
          float Eo = exp2n_(acc[m][3][r]);
          float Ec = exp2_(ccs);
          hx[q2] = (Ec - 1.f) * rcp_((1.f + Eo) * (Ec + 1.f));
        }
        unsigned pk = cvtpk(hx[0], hx[1]);
        const int s0 = 16 * m + 4 * quad + 2 * rp;
        Ahi[pn][s0][u] = (unsigned short)pk;
        Ahi[pn][s0 + 1][u] = (unsigned short)(pk >> 16);
      }
  }

  // ---- peeled t=5: p=1, pn=0. gemm1(5) reads plane1; hi results -> plane0;
  //      lo values stashed in regs, then written to plane1 after a barrier.
  __syncthreads();  // [h0_5 | h1_4] visible in plane 1; plane-0 WAR done
#pragma unroll
  for (int m = 0; m < 4; ++m)
#pragma unroll
    for (int n = 0; n < 4; ++n)
#pragma unroll
      for (int r = 0; r < 4; ++r) acc[m][n][r] = b1v[n];
  gemm1t<4, 8, 2>(wsu + OFF_L1, 256, colsL, Ahi[1], l16, quad, acc);

  unsigned int lopack[16];  // [4m+r] = cvtpk(last-lo, mean-lo)
#pragma unroll
  for (int m = 0; m < 4; ++m)
#pragma unroll
    for (int rp = 0; rp < 2; ++rp) {
      float hx[2], mn[2];
#pragma unroll
      for (int q2 = 0; q2 < 2; ++q2) {
        const int r = 2 * rp + q2;
        float Ai = 1.f + exp2n_(acc[m][0][r]);
        float Af = 1.f + exp2n_(acc[m][1][r]);
        float Eg = exp2_(acc[m][2][r]);
        float Ag = Eg + 1.f;
        float Ngk = __builtin_fmaf(Eg, K2F, -K2F);
        float P = Ai * Ag;
        float Rr = rcp_(Af * P);
        float ccs = __builtin_fmaf(c1[m][r], P, Ngk * Af) * Rr;
        float Eo = exp2n_(acc[m][3][r]);
        float Ec = exp2_(ccs);
        float h = (Ec - 1.f) * rcp_((1.f + Eo) * (Ec + 1.f));
        hx[q2] = h;
        mn[q2] = (meanh[m][r] + h) * (1.f / 6.f);
      }
      const int s0 = 16 * m + 4 * quad + 2 * rp;
      unsigned pkh = cvtpk(hx[0], hx[1]);
      Ahi[0][s0][128 + u] = (unsigned short)pkh;        // last hi (pair)
      Ahi[0][s0 + 1][128 + u] = (unsigned short)(pkh >> 16);
      unsigned pkm = cvtpk(mn[0], mn[1]);
      Ahi[0][s0][u] = (unsigned short)pkm;              // mean hi (pair)
      Ahi[0][s0 + 1][u] = (unsigned short)(pkm >> 16);
      lopack[4 * m + 2 * rp] =
          cvtpk(hx[0] - asf(pkh << 16), mn[0] - asf(pkm << 16));
      lopack[4 * m + 2 * rp + 1] =
          cvtpk(hx[1] - asf(pkh & 0xffff0000u), mn[1] - asf(pkm & 0xffff0000u));
    }

  __syncthreads();  // all gemm1(5) plane-1 reads done -> safe to overwrite plane 1
#pragma unroll
  for (int m = 0; m < 4; ++m)
#pragma unroll
    for (int r = 0; r < 4; ++r) {
      const int s = 16 * m + 4 * quad + r;
      const unsigned int v = lopack[4 * m + r];
      Ahi[1][s][128 + u] = (unsigned short)(v & 0xffffu);  // last lo
      Ahi[1][s][u] = (unsigned short)(v >> 16);            // mean lo
    }

  // ---- dense head: 3 layers (3-term), IN-PLACE on planes 0(hi)/1(lo) ----
  int colsD[2];
  colsD[0] = 32 * wv; colsD[1] = 32 * wv + 16;

#pragma unroll 1
  for (int layer = 0; layer < 3; ++layer) {
    const int base = (layer == 0) ? OFF_D0 : ((layer == 1) ? OFF_D1 : OFF_D2);
    const float* bd = (layer == 0) ? bd0 : ((layer == 1) ? bd1 : bd2);
    float bdv[2];
#pragma unroll
    for (int n = 0; n < 2; ++n) bdv[n] = bd[colsD[n] + l16] * K2F;
#pragma unroll
    for (int m = 0; m < 4; ++m)
#pragma unroll
      for (int n = 0; n < 2; ++n)
#pragma unroll
        for (int r = 0; r < 4; ++r) acc[m][n][r] = bdv[n];
    __syncthreads();  // prev writes (lo-init / prev layer) visible
    gemm3t<2, 8, 2>(wsu + base, 512, colsD, Ahi[0], Ahi[1], l16, quad, acc);
    __syncthreads();  // all reads of planes 0/1 done before in-place overwrite
#pragma unroll
    for (int m = 0; m < 4; ++m)
#pragma unroll
      for (int r = 0; r < 4; ++r) {
        const int s = 16 * m + 4 * quad + r;
        float a0 = tanh_s(acc[m][0][r]);
        float a1 = tanh_s(acc[m][1][r]);
        unsigned pk = cvtpk(a0, a1);                 // column pair (n=0,1)
        const int ci0 = colsD[0] + l16, ci1 = colsD[1] + l16;
        Ahi[0][s][ci0] = (unsigned short)pk;
        Ahi[0][s][ci1] = (unsigned short)(pk >> 16);
        unsigned pkl = cvtpk(a0 - asf(pk << 16), a1 - asf(pk & 0xffff0000u));
        Ahi[1][s][ci0] = (unsigned short)pkl;
        Ahi[1][s][ci1] = (unsigned short)(pkl >> 16);
      }
  }
  __syncthreads();

  // ---- output layer (3-term): waves 0..3 handle m-tile wv; read planes 0/1 ----
  if (wv < 4) {
    f32x4 oacc = {0.f, 0.f, 0.f, 0.f};
    const unsigned short* bp = wsu + OFF_OUT + (size_t)l16 * 512 + quad * 16;
    const unsigned short* aph = &Ahi[0][16 * wv + l16][quad * 8];
    const unsigned short* apl = &Ahi[1][16 * wv + l16][quad * 8];
#pragma unroll 1
    for (int ki = 0; ki < 8; ++ki) {
      bf16x8 ah = *(const bf16x8*)aph;
      bf16x8 al = *(const bf16x8*)apl;
      bf16x8 bh = *(const bf16x8*)bp;
      bf16x8 bl = *(const bf16x8*)(bp + 8);
      oacc = __builtin_amdgcn_mfma_f32_16x16x32_bf16(ah, bh, oacc, 0, 0, 0);
      oacc = __builtin_amdgcn_mfma_f32_16x16x32_bf16(al, bh, oacc, 0, 0, 0);
      oacc = __builtin_amdgcn_mfma_f32_16x16x32_bf16(ah, bl, oacc, 0, 0, 0);
      aph += 32; apl += 32; bp += 64;
    }
    float bo = (l16 < 4) ? bout[l16] : 0.f;
#pragma unroll
    for (int r = 0; r < 4; ++r) {
      if (l16 < 4) {
        int s = sb + 16 * wv + 4 * quad + r;
        out[s * 4 + l16] = oacc[r] + bo;
      }
    }
  }
}

extern "C" void kernel_launch(void* const* d_in, const int* in_sizes, int n_in,
                              void* d_out, int out_size, void* d_ws, size_t ws_size,
                              hipStream_t stream) {
  (void)in_sizes; (void)n_in; (void)out_size; (void)ws_size;
  const float* x    = (const float*)d_in[0];
  const float* y    = (const float*)d_in[1];
  const float* Wih0 = (const float*)d_in[2];
  const float* Whh0 = (const float*)d_in[3];
  const float* b0   = (const float*)d_in[4];
  const float* Wih1 = (const float*)d_in[5];
  const float* Whh1 = (const float*)d_in[6];
  const float* b1   = (const float*)d_in[7];
  const float* Wd0  = (const float*)d_in[8];
  const float* bd0  = (const float*)d_in[9];
  const float* Wd1  = (const float*)d_in[10];
  const float* bd1  = (const float*)d_in[11];
  const float* Wd2  = (const float*)d_in[12];
  const float* bd2  = (const float*)d_in[13];
  const float* Wout = (const float*)d_in[14];
  const float* bout = (const float*)d_in[15];
  unsigned short* ws = (unsigned short*)d_ws;
  float* out = (float*)d_out;

  prep_k<<<dim3(388), dim3(256), 0, stream>>>(Whh0, Wih1, Whh1, Wd0, Wd1, Wd2, Wout, ws);
  fused_k<<<dim3(65536 / TM), dim3(512), 0, stream>>>(x, y, Wih0, b0, b1, bd0, bd1, bd2,
                                                      bout, ws, out);
}